// Round 14
// baseline (109.817 us; speedup 1.0000x reference)
//
#include <hip/hip_runtime.h>

#define NGRAPH 128
#define NBLK   2048
#define BS     256

// Fixed-point packing: one u64 per (sum,count) pair.
//   bits [0,42)  : sum of edge_var scaled by 2^18  (worst case ~2^40)
//   bits [42,64) : edge count (max 3.2M < 2^22)
#define FIX_SCALE 262144.0f          // 2^18
#define CNT_SHIFT 42

typedef int iv4 __attribute__((ext_vector_type(4)));   // native vector: OK for nontemporal builtin

// d_ws layout: [0, N*16)        packed float4 per node {x, y, gid_bits, 0}
//              [+0, +2MB)       part[NGRAPH][NBLK] u64 partials (TRANSPOSED)

__global__ __launch_bounds__(BS) void edgevar_pack(
    const float2* __restrict__ pos,
    const int*    __restrict__ batch,
    float4*       __restrict__ packed,
    float*        __restrict__ out,
    int N) {
  const int i = blockIdx.x * BS + threadIdx.x;
  if (blockIdx.x == 0 && threadIdx.x == 0) out[0] = 0.f;  // d_out is poisoned each iter
  if (i < N) {
    float2 p = pos[i];
    packed[i] = make_float4(p.x, p.y, __int_as_float(batch[i]), 0.f);
  }
}

__global__ __launch_bounds__(BS) void edgevar_stage1(
    const float4* __restrict__ packed,
    const int*    __restrict__ ei,
    unsigned long long* __restrict__ part,
    int E) {
  __shared__ unsigned long long s_acc[4][NGRAPH];   // 4-way privatized, 4KB
  {
    unsigned long long* f = &s_acc[0][0];
    if (threadIdx.x < 2 * NGRAPH) {
      f[threadIdx.x] = 0ull;
      f[threadIdx.x + 2 * NGRAPH] = 0ull;
    }
  }
  __syncthreads();

  const int cp  = threadIdx.x & 3;
  const int tid = blockIdx.x * BS + threadIdx.x;
  const int nth = NBLK * BS;
  const int E4  = E >> 2;
  const iv4*    __restrict__ s4  = (const iv4*)ei;
  const iv4*    __restrict__ d4  = (const iv4*)(ei + E);
  const float2* __restrict__ pp2 = (const float2*)packed;

  for (int i = tid; i < E4; i += nth) {
    iv4 s = __builtin_nontemporal_load(&s4[i]);   // read-once stream: don't thrash L2
    iv4 d = __builtin_nontemporal_load(&d4[i]);
    int ss[4] = {s.x, s.y, s.z, s.w};
    int dd[4] = {d.x, d.y, d.z, d.w};
#pragma unroll
    for (int k = 0; k < 4; ++k) {
      float4 a = packed[ss[k]];          // 16B txn: pos + gid (L2-resident)
      float2 b = pp2[2 * dd[k]];         // 8B txn: pos
      float dx = b.x - a.x, dy = b.y - a.y;
      float v  = sqrtf(dx * dx + dy * dy) - 1.f;
      v *= v;
      int g = __float_as_int(a.z);
      unsigned long long contrib =
          (1ull << CNT_SHIFT) | (unsigned long long)(v * FIX_SCALE + 0.5f);
      atomicAdd(&s_acc[cp][g], contrib);   // single LDS atomic per edge
    }
  }
  for (int e = (E4 << 2) + tid; e < E; e += nth) {   // tail safety
    float4 a = packed[ei[e]];
    float2 b = pp2[2 * ei[e + E]];
    float dx = b.x - a.x, dy = b.y - a.y;
    float v  = sqrtf(dx * dx + dy * dy) - 1.f;
    v *= v;
    int g = __float_as_int(a.z);
    unsigned long long contrib =
        (1ull << CNT_SHIFT) | (unsigned long long)(v * FIX_SCALE + 0.5f);
    atomicAdd(&s_acc[cp][g], contrib);
  }

  __syncthreads();
  if (threadIdx.x < NGRAPH) {
    unsigned long long t = s_acc[0][threadIdx.x] + s_acc[1][threadIdx.x]
                         + s_acc[2][threadIdx.x] + s_acc[3][threadIdx.x];
    // transposed: part[slot][block] — scattered 8B stores (128/block, cheap),
    // makes stage2 row-contiguous
    part[(size_t)threadIdx.x * NBLK + blockIdx.x] = t;
  }
}

__global__ __launch_bounds__(BS) void edgevar_stage2(
    const unsigned long long* __restrict__ part,
    float* __restrict__ out) {
  const int g = blockIdx.x;          // one block per graph
  const int t = threadIdx.x;
  const unsigned long long* row = part + (size_t)g * NBLK;
  unsigned long long acc = 0ull;     // exact integer accumulation
#pragma unroll
  for (int k = 0; k < NBLK / BS; ++k) acc += row[t + k * BS];
  for (int off = 32; off; off >>= 1) acc += __shfl_down(acc, off);
  __shared__ unsigned long long wsum[4];
  if ((t & 63) == 0) wsum[t >> 6] = acc;
  __syncthreads();
  if (t == 0) {
    unsigned long long tot = wsum[0] + wsum[1] + wsum[2] + wsum[3];
    unsigned int       cnt = (unsigned int)(tot >> CNT_SHIFT);
    float sum = (float)(tot & ((1ull << CNT_SHIFT) - 1ull)) * (1.0f / FIX_SCALE);
    float var = sum / fmaxf((float)cnt, 1.f);
    atomicAdd(out, var * (1.0f / NGRAPH));   // 128 atomics total — fuses stage3
  }
}

extern "C" void kernel_launch(void* const* d_in, const int* in_sizes, int n_in,
                              void* d_out, int out_size, void* d_ws, size_t ws_size,
                              hipStream_t stream) {
  const float2* pos   = (const float2*)d_in[0];
  const int*    ei    = (const int*)d_in[1];
  const int*    batch = (const int*)d_in[2];
  float*        out   = (float*)d_out;
  const int N = in_sizes[0] / 2;
  const int E = in_sizes[1] / 2;

  float4*             packed = (float4*)d_ws;
  unsigned long long* part   =
      (unsigned long long*)((char*)d_ws + (size_t)N * sizeof(float4));

  hipLaunchKernelGGL(edgevar_pack, dim3((N + BS - 1) / BS), dim3(BS), 0, stream,
                     pos, batch, packed, out, N);
  hipLaunchKernelGGL(edgevar_stage1, dim3(NBLK), dim3(BS), 0, stream,
                     packed, ei, part, E);
  hipLaunchKernelGGL(edgevar_stage2, dim3(NGRAPH), dim3(BS), 0, stream,
                     part, out);
}